// Round 4
// baseline (147.626 us; speedup 1.0000x reference)
//
#include <hip/hip_runtime.h>

// B=1024, D=1024 -> tokens N_TOK=4096, EMB=256, CODES=512.
// d_out (float32): out[1048576], loss[1], idx_as_float[4096].

typedef _Float16 half8 __attribute__((ext_vector_type(8)));
typedef _Float16 half4 __attribute__((ext_vector_type(4)));
typedef float floatx4 __attribute__((ext_vector_type(4)));

#define LO_SCALE 2048.0f
#define INV_LO_SCALE (1.0f / 2048.0f)

// Direct global->LDS DMA, 16B per lane. LDS dest must be wave-uniform base;
// lane i lands at base + i*16B.
__device__ __forceinline__ void gl_lds16(const _Float16* g, _Float16* l)
{
    __builtin_amdgcn_global_load_lds(
        (const __attribute__((address_space(1))) void*)g,
        (__attribute__((address_space(3))) void*)l, 16, 0, 0);
}

// LDS tile: 64 rows x 64 halves (128B row = 8 chunks of 16B).
// Stored chunk position p holds global k-chunk (p ^ (row&7)).  Staging
// pre-applies the XOR on the GLOBAL source so the DMA write stays linear.
// Fragment read (16x16x32 f16, validated layout): lane (fr,fg) of row needs
// k = ks*32 + 4fg + {0..3} and ks*32 + 16 + 4fg + {0..3}  ->  two b64 reads.
__device__ __forceinline__ half8 rfrag(const _Float16* m, int row, int ks, int fg)
{
    const int sw = row & 7;
    const int c1 = ((ks << 2) + (fg >> 1)) ^ sw;
    const int c2 = ((ks << 2) + (fg >> 1) + 2) ^ sw;
    const int hs = (fg & 1) << 2;
    const int rb = row << 6;
    half4 x = *reinterpret_cast<const half4*>(&m[rb + (c1 << 3) + hs]);
    half4 y = *reinterpret_cast<const half4*>(&m[rb + (c2 << 3) + hs]);
    half8 r;
    r[0] = x[0]; r[1] = x[1]; r[2] = x[2]; r[3] = x[3];
    r[4] = y[0]; r[5] = y[1]; r[6] = y[2]; r[7] = y[3];
    return r;
}

// ---------------------------------------------------------------------------
// C = act(A @ B^T + bias), fp16 3-term split emulating fp32.
// A: h/l [M][K] f16.  B: h/l [N][K] f16.  512 thr / 8 waves; tile 64x64.
// Wave w: ks = w>>2 (K-split), quadrant q = w&3 -> 32x32 (2x2 of 16x16x32).
// Double-buffered LDS staged entirely by global_load_lds; one barrier/iter.
// K-split partials combined via a 16KB LDS reduction at the end.
// ---------------------------------------------------------------------------
template <bool RELU, bool WF32, bool WSPLIT>
__global__ __launch_bounds__(512) void gemm_k(
    const _Float16* __restrict__ Ah, const _Float16* __restrict__ Al,
    const _Float16* __restrict__ Bh, const _Float16* __restrict__ Bl,
    const float* __restrict__ bias,
    float* __restrict__ Cf, _Float16* __restrict__ Ch, _Float16* __restrict__ Cl,
    int N, int K)
{
    __shared__ __align__(16) _Float16 sm[2][4][64 * 64];  // 64KB

    const int tid = threadIdx.x;
    const int m0 = blockIdx.y * 64, n0 = blockIdx.x * 64;
    const int w = tid >> 6, lane = tid & 63;

    // staging role: wave w stages matrix w>>1, row-half w&1 (4 DMA instrs)
    const int mat = w >> 1;
    const int half32 = (w & 1) * 32;
    const _Float16* gsrc = (mat == 0) ? Ah : (mat == 1) ? Al : (mat == 2) ? Bh : Bl;
    const int rb0 = (mat < 2) ? m0 : n0;
    const int srow_lo = lane >> 3;   // row within 8-row DMA group
    const int sc = lane & 7;         // 16B chunk within row

    // compute role
    const int ks = w >> 2, q = w & 3;
    const int wm = (q >> 1) * 32, wn = (q & 1) * 32;
    const int fr = lane & 15, fg = lane >> 4;

    floatx4 hh[2][2] = {};
    floatx4 mx[2][2] = {};

    const int NT = K >> 6;

    auto STAGE = [&](int buf, int t) {
        const int kb = t << 6;
        #pragma unroll
        for (int j = 0; j < 4; ++j) {
            const int row = half32 + (j << 3) + srow_lo;
            const _Float16* g = gsrc + (size_t)(rb0 + row) * K + kb
                              + ((sc ^ (row & 7)) << 3);
            gl_lds16(g, &sm[buf][mat][(half32 + (j << 3)) << 6]);
        }
    };

    STAGE(0, 0);
    __syncthreads();

    for (int t = 0; t < NT; ++t) {
        const int cur = t & 1;
        if (t + 1 < NT) STAGE(cur ^ 1, t + 1);   // prefetch under compute

        half8 a_h[2], a_l[2], b_h[2], b_l[2];
        #pragma unroll
        for (int i = 0; i < 2; ++i) {
            a_h[i] = rfrag(sm[cur][0], wm + (i << 4) + fr, ks, fg);
            a_l[i] = rfrag(sm[cur][1], wm + (i << 4) + fr, ks, fg);
            b_h[i] = rfrag(sm[cur][2], wn + (i << 4) + fr, ks, fg);
            b_l[i] = rfrag(sm[cur][3], wn + (i << 4) + fr, ks, fg);
        }
        #pragma unroll
        for (int i = 0; i < 2; ++i)
            #pragma unroll
            for (int j = 0; j < 2; ++j) {
                hh[i][j] = __builtin_amdgcn_mfma_f32_16x16x32_f16(a_h[i], b_h[j], hh[i][j], 0, 0, 0);
                mx[i][j] = __builtin_amdgcn_mfma_f32_16x16x32_f16(a_h[i], b_l[j], mx[i][j], 0, 0, 0);
                mx[i][j] = __builtin_amdgcn_mfma_f32_16x16x32_f16(a_l[i], b_h[j], mx[i][j], 0, 0, 0);
            }
        __syncthreads();   // implicit vmcnt drain -> next buf staged & safe
    }

    // K-split reduction: waves 4-7 dump partials; waves 0-3 combine + write.
    float* red = (float*)&sm[0][0][0];  // 16KB, buffers dead
    if (w >= 4) {
        #pragma unroll
        for (int i = 0; i < 2; ++i)
            #pragma unroll
            for (int j = 0; j < 2; ++j)
                #pragma unroll
                for (int r = 0; r < 4; ++r)
                    red[q * 1024 + ((i << 4) + (fg << 2) + r) * 32 + (j << 4) + fr]
                        = hh[i][j][r] + mx[i][j][r] * INV_LO_SCALE;
    }
    __syncthreads();
    if (w < 4) {
        #pragma unroll
        for (int j = 0; j < 2; ++j) {
            const int col = n0 + wn + (j << 4) + fr;
            const float bv = bias ? bias[col] : 0.0f;
            #pragma unroll
            for (int i = 0; i < 2; ++i)
                #pragma unroll
                for (int r = 0; r < 4; ++r) {
                    const int rl = (i << 4) + (fg << 2) + r;
                    float v = hh[i][j][r] + mx[i][j][r] * INV_LO_SCALE
                            + red[q * 1024 + rl * 32 + (j << 4) + fr] + bv;
                    if (RELU) v = fmaxf(v, 0.0f);
                    const size_t o = (size_t)(m0 + wm + rl) * N + col;
                    if (WF32) Cf[o] = v;
                    if (WSPLIT) {
                        const _Float16 hi = (_Float16)v;
                        Ch[o] = hi;
                        Cl[o] = (_Float16)((v - (float)hi) * LO_SCALE);
                    }
                }
        }
    }
}

// ---------------------------------------------------------------------------
// fp32 -> f16 hi/lo split, flat (obs). n = 1M elems: 512 blocks x 256 x 8.
// ---------------------------------------------------------------------------
__global__ __launch_bounds__(256) void split_kernel(
    const float* __restrict__ X, _Float16* __restrict__ H, _Float16* __restrict__ L)
{
    const int i = (blockIdx.x * 256 + threadIdx.x) * 8;
    float4 a = *reinterpret_cast<const float4*>(&X[i]);
    float4 b = *reinterpret_cast<const float4*>(&X[i + 4]);
    float xs[8] = {a.x, a.y, a.z, a.w, b.x, b.y, b.z, b.w};
    half8 h, lo;
    #pragma unroll
    for (int j = 0; j < 8; ++j) {
        const _Float16 hi = (_Float16)xs[j];
        h[j] = hi;
        lo[j] = (_Float16)((xs[j] - (float)hi) * LO_SCALE);
    }
    *reinterpret_cast<half8*>(&H[i]) = h;
    *reinterpret_cast<half8*>(&L[i]) = lo;
}

// ---------------------------------------------------------------------------
// Split + transpose all three weights: W [1024][1024] f32 -> [N][K] h/l f16.
// ---------------------------------------------------------------------------
__global__ __launch_bounds__(256) void splitT3_kernel(
    const float* __restrict__ W1, const float* __restrict__ W2, const float* __restrict__ W3,
    _Float16* __restrict__ T1h, _Float16* __restrict__ T1l,
    _Float16* __restrict__ T2h, _Float16* __restrict__ T2l,
    _Float16* __restrict__ T3h, _Float16* __restrict__ T3l)
{
    const int z = blockIdx.z;
    const float* Wm = (z == 0) ? W1 : (z == 1) ? W2 : W3;
    _Float16* Th = (z == 0) ? T1h : (z == 1) ? T2h : T3h;
    _Float16* Tl = (z == 0) ? T1l : (z == 1) ? T2l : T3l;

    __shared__ float tile[64][65];
    const int tid = threadIdx.x;
    const int kb = blockIdx.y * 64, nb = blockIdx.x * 64;
    {
        const int kr = tid >> 2, c0 = (tid & 3) * 16;
        #pragma unroll
        for (int c = 0; c < 16; c += 4) {
            float4 v = *reinterpret_cast<const float4*>(
                &Wm[(size_t)(kb + kr) * 1024 + nb + c0 + c]);
            tile[kr][c0 + c] = v.x; tile[kr][c0 + c + 1] = v.y;
            tile[kr][c0 + c + 2] = v.z; tile[kr][c0 + c + 3] = v.w;
        }
    }
    __syncthreads();
    {
        const int nr = tid >> 2, k0 = (tid & 3) * 16;
        half8 h[2], lo[2];
        #pragma unroll
        for (int c = 0; c < 16; ++c) {
            const float x = tile[k0 + c][nr];
            const _Float16 hi = (_Float16)x;
            h[c >> 3][c & 7] = hi;
            lo[c >> 3][c & 7] = (_Float16)((x - (float)hi) * LO_SCALE);
        }
        const size_t o = (size_t)(nb + nr) * 1024 + kb + k0;
        *reinterpret_cast<half8*>(&Th[o]) = h[0];
        *reinterpret_cast<half8*>(&Th[o + 8]) = h[1];
        *reinterpret_cast<half8*>(&Tl[o]) = lo[0];
        *reinterpret_cast<half8*>(&Tl[o + 8]) = lo[1];
    }
}

// ---------------------------------------------------------------------------
// Codebook split + squared norms. One wave per code.
// ---------------------------------------------------------------------------
__global__ void cb_split_kernel(const float* __restrict__ CB,
                                _Float16* __restrict__ CBh, _Float16* __restrict__ CBl,
                                float* __restrict__ cnorm)
{
    const int k = blockIdx.x, lane = threadIdx.x;  // 64
    const int i = k * 256 + lane * 4;
    float4 c = *reinterpret_cast<const float4*>(&CB[i]);
    float xs[4] = {c.x, c.y, c.z, c.w};
    half4 h, lo;
    float s = 0.f;
    #pragma unroll
    for (int j = 0; j < 4; ++j) {
        const _Float16 hi = (_Float16)xs[j];
        h[j] = hi;
        lo[j] = (_Float16)((xs[j] - (float)hi) * LO_SCALE);
        s += xs[j] * xs[j];
    }
    *reinterpret_cast<half4*>(&CBh[i]) = h;
    *reinterpret_cast<half4*>(&CBl[i]) = lo;
    #pragma unroll
    for (int off = 32; off; off >>= 1) s += __shfl_down(s, off);
    if (lane == 0) cnorm[k] = s;
}

// ---------------------------------------------------------------------------
// VQ: one wave per token; 8 tokens per 512-thr block. Per-block loss partial.
// ---------------------------------------------------------------------------
__global__ __launch_bounds__(512) void vq_kernel(
    const _Float16* __restrict__ Fh, const _Float16* __restrict__ Fl,
    const float* __restrict__ S, const float* __restrict__ CB,
    const float* __restrict__ cnorm,
    float* __restrict__ out, float* __restrict__ pl, float* __restrict__ idx_out)
{
    const int wid = threadIdx.x >> 6, lane = threadIdx.x & 63;
    const int n = blockIdx.x * 8 + wid;

    float best = 3.4e38f;
    int bidx = 0x7fffffff;
    #pragma unroll
    for (int j = 0; j < 8; ++j) {
        const int k = j * 64 + lane;
        const float v = fmaf(-2.0f, S[(size_t)n * 512 + k], cnorm[k]);
        if (v < best) { best = v; bidx = k; }   // strict <: first occurrence
    }
    #pragma unroll
    for (int off = 32; off; off >>= 1) {
        const float ov = __shfl_down(best, off);
        const int oi = __shfl_down(bidx, off);
        if (ov < best || (ov == best && oi < bidx)) { best = ov; bidx = oi; }
    }
    bidx = __shfl(bidx, 0);
    best = __shfl(best, 0);

    const int base = n * 256 + lane * 4;
    half4 h4 = *reinterpret_cast<const half4*>(&Fh[base]);
    half4 l4 = *reinterpret_cast<const half4*>(&Fl[base]);
    float zn = 0.f;
    #pragma unroll
    for (int j = 0; j < 4; ++j) {
        const float z = (float)h4[j] + (float)l4[j] * INV_LO_SCALE;
        zn = fmaf(z, z, zn);
    }
    #pragma unroll
    for (int off = 32; off; off >>= 1) zn += __shfl_down(zn, off);

    float4 q4 = *reinterpret_cast<const float4*>(&CB[(size_t)bidx * 256 + lane * 4]);
    *reinterpret_cast<float4*>(&out[(size_t)n * 256 + lane * 4]) = q4;

    __shared__ float part[8];
    if (lane == 0) {
        part[wid] = zn + best;      // = ||z - q||^2 for this token
        idx_out[n] = (float)bidx;
    }
    __syncthreads();
    if (threadIdx.x == 0) {
        float s = 0.f;
        #pragma unroll
        for (int i = 0; i < 8; ++i) s += part[i];
        pl[blockIdx.x] = s;
    }
}

__global__ __launch_bounds__(512) void finalize_kernel(
    const float* __restrict__ pl, float* __restrict__ loss_out)
{
    float s = pl[threadIdx.x];
    #pragma unroll
    for (int off = 32; off; off >>= 1) s += __shfl_down(s, off);
    __shared__ float p[8];
    if ((threadIdx.x & 63) == 0) p[threadIdx.x >> 6] = s;
    __syncthreads();
    if (threadIdx.x == 0) {
        float t = 0.f;
        #pragma unroll
        for (int i = 0; i < 8; ++i) t += p[i];
        loss_out[0] = 1.25f * t / 1048576.0f;
    }
}

// ---------------------------------------------------------------------------
extern "C" void kernel_launch(void* const* d_in, const int* in_sizes, int n_in,
                              void* d_out, int out_size, void* d_ws, size_t ws_size,
                              hipStream_t stream)
{
    const float* obs = (const float*)d_in[0];
    const float* W1  = (const float*)d_in[1];
    const float* b1  = (const float*)d_in[2];
    const float* W2  = (const float*)d_in[3];
    const float* b2  = (const float*)d_in[4];
    const float* W3  = (const float*)d_in[5];
    const float* b3  = (const float*)d_in[6];
    const float* CB  = (const float*)d_in[7];

    float* out = (float*)d_out;
    float* loss_out = out + 1048576;
    float* idx_out  = out + 1048577;

    char* Wp = (char*)d_ws;   // no aliasing this round — plenty of ws
    _Float16* Oh    = (_Float16*)(Wp + (0u  << 20));
    _Float16* Ol    = (_Float16*)(Wp + (2u  << 20));
    _Float16* W1t_h = (_Float16*)(Wp + (4u  << 20));
    _Float16* W1t_l = (_Float16*)(Wp + (6u  << 20));
    _Float16* W2t_h = (_Float16*)(Wp + (8u  << 20));
    _Float16* W2t_l = (_Float16*)(Wp + (10u << 20));
    _Float16* W3t_h = (_Float16*)(Wp + (12u << 20));
    _Float16* W3t_l = (_Float16*)(Wp + (14u << 20));
    _Float16* H1_h  = (_Float16*)(Wp + (16u << 20));
    _Float16* H1_l  = (_Float16*)(Wp + (18u << 20));
    _Float16* H2_h  = (_Float16*)(Wp + (20u << 20));
    _Float16* H2_l  = (_Float16*)(Wp + (22u << 20));
    _Float16* F_h   = (_Float16*)(Wp + (24u << 20));
    _Float16* F_l   = (_Float16*)(Wp + (26u << 20));
    float*    S     = (float*)(Wp + (28u << 20));          // 8MB
    _Float16* CB_h  = (_Float16*)(Wp + (36u << 20));
    _Float16* CB_l  = (_Float16*)(Wp + (36u << 20) + 512 * 256 * 2);
    float*    cn    = (float*)(Wp + (36u << 20) + 2 * 512 * 256 * 2);
    float*    pl    = cn + 512;

    split_kernel<<<512, 256, 0, stream>>>(obs, Oh, Ol);
    splitT3_kernel<<<dim3(16, 16, 3), 256, 0, stream>>>(
        W1, W2, W3, W1t_h, W1t_l, W2t_h, W2t_l, W3t_h, W3t_l);
    cb_split_kernel<<<512, 64, 0, stream>>>(CB, CB_h, CB_l, cn);

    gemm_k<true, false, true><<<dim3(16, 16), 512, 0, stream>>>(
        Oh, Ol, W1t_h, W1t_l, b1, nullptr, H1_h, H1_l, 1024, 1024);
    gemm_k<true, false, true><<<dim3(16, 16), 512, 0, stream>>>(
        H1_h, H1_l, W2t_h, W2t_l, b2, nullptr, H2_h, H2_l, 1024, 1024);
    gemm_k<false, false, true><<<dim3(16, 16), 512, 0, stream>>>(
        H2_h, H2_l, W3t_h, W3t_l, b3, nullptr, F_h, F_l, 1024, 1024);
    // S = z @ CB^T : [4096, 512], K=256 -> 512 blocks, 2/CU
    gemm_k<false, true, false><<<dim3(8, 64), 512, 0, stream>>>(
        F_h, F_l, CB_h, CB_l, nullptr, S, nullptr, nullptr, 512, 256);

    vq_kernel<<<512, 512, 0, stream>>>(F_h, F_l, S, CB, cn, out, pl, idx_out);
    finalize_kernel<<<1, 512, 0, stream>>>(pl, loss_out);
}

// Round 5
// 140.333 us; speedup vs baseline: 1.0520x; 1.0520x over previous
//
#include <hip/hip_runtime.h>

// B=1024, D=1024 -> tokens N_TOK=4096, EMB=256, CODES=512.
// d_out (float32): out[1048576], loss[1], idx_as_float[4096].

typedef _Float16 half8 __attribute__((ext_vector_type(8)));
typedef _Float16 half4 __attribute__((ext_vector_type(4)));
typedef float floatx4 __attribute__((ext_vector_type(4)));

#define LO_SCALE 2048.0f
#define INV_LO_SCALE (1.0f / 2048.0f)

// ---------------------------------------------------------------------------
// k-interleaved storage: within each 64-k group, position of element k is
//   pos(k) = (k&32) | ((k&12)<<1) | ((k&16)>>2) | (k&3)
// so that MFMA fragment (ks, fg) = halves {ks*32+4fg+j, ks*32+16+4fg+j} is
// one contiguous 16B chunk (# = ks*4+fg). Producers write this layout.
// ---------------------------------------------------------------------------
__device__ __forceinline__ int remap4(int k0)   // k0 aligned to 4, within 64
{
    return (k0 & 32) | ((k0 & 12) << 1) | ((k0 & 16) >> 2);
}
__device__ __forceinline__ int remap1(int k)    // full column index
{
    return (k & ~63) | (k & 32) | ((k & 12) << 1) | ((k & 16) >> 2) | (k & 3);
}

// Direct global->LDS DMA, 16B/lane; lane i lands at ldsbase + i*16.
__device__ __forceinline__ void gl_lds16(const _Float16* g, _Float16* l)
{
    __builtin_amdgcn_global_load_lds(
        (const __attribute__((address_space(1))) void*)g,
        (__attribute__((address_space(3))) void*)l, 16, 0, 0);
}

// LDS row = 64 halves (128B) = 8 chunks of 16B; stored chunk p holds global
// chunk p^(row&7) (staging pre-XORs the global source; DMA write is linear).
__device__ __forceinline__ half8 rfrag(const _Float16* m, int row, int ks, int fg)
{
    const int ch = ((ks << 2) + fg) ^ (row & 7);
    return *reinterpret_cast<const half8*>(&m[(row << 6) + (ch << 3)]);
}

// ---------------------------------------------------------------------------
// C = act(A @ B^T + bias), fp16 3-term split emulating fp32.
// A: h/l [M][K], B: h/l [N][K], both k-interleaved f16.
// Tile 32x64, 256 thr / 4 waves, wave tile 16x32 (2 frags of 16x16, K-full).
// Double-buffered LDS staged by global_load_lds; one barrier per K-iter.
// Grid: (N/64, M/32) -> 512 blocks for 1024x1024 (2 blocks/CU).
// ---------------------------------------------------------------------------
template <bool RELU, bool WF32, bool WSPLIT>
__global__ __launch_bounds__(256) void gemm_k(
    const _Float16* __restrict__ Ah, const _Float16* __restrict__ Al,
    const _Float16* __restrict__ Bh, const _Float16* __restrict__ Bl,
    const float* __restrict__ bias,
    float* __restrict__ Cf, _Float16* __restrict__ Ch, _Float16* __restrict__ Cl,
    int N, int K)
{
    // rows 0..31: Ah, 32..63: Al, 64..127: Bh, 128..191: Bl
    __shared__ __align__(16) _Float16 sm[2][192 * 64];   // 48KB

    const int tid = threadIdx.x;
    const int m0 = blockIdx.y * 32, n0 = blockIdx.x * 64;
    const int w = tid >> 6, lane = tid & 63;
    const int srow = lane >> 3, sc = lane & 7;

    const int wm = (w & 1) * 16, wn = (w >> 1) * 32;
    const int fr = lane & 15, fg = lane >> 4;

    floatx4 hh[2] = {};   // Ah*Bh
    floatx4 m1[2] = {};   // Ah*Bl
    floatx4 m2[2] = {};   // Al*Bh

    const int NT = K >> 6;

    auto STAGE = [&](int buf, int t) {
        const int kb = t << 6;
        #pragma unroll
        for (int s = 0; s < 6; ++s) {
            const int task = w * 6 + s;          // 0..23, wave-uniform
            const _Float16* gb;
            int grow, lrow;
            if (task < 4)       { gb = Ah; grow = m0 + task * 8;        lrow = task * 8; }
            else if (task < 8)  { gb = Al; grow = m0 + (task - 4) * 8;  lrow = 32 + (task - 4) * 8; }
            else if (task < 16) { gb = Bh; grow = n0 + (task - 8) * 8;  lrow = 64 + (task - 8) * 8; }
            else                { gb = Bl; grow = n0 + (task - 16) * 8; lrow = 128 + (task - 16) * 8; }
            const _Float16* g = gb + (size_t)(grow + srow) * K + kb + ((sc ^ srow) << 3);
            gl_lds16(g, &sm[buf][lrow << 6]);
        }
    };

    STAGE(0, 0);
    __syncthreads();

    for (int t = 0; t < NT; ++t) {
        const int cur = t & 1;
        if (t + 1 < NT) STAGE(cur ^ 1, t + 1);   // prefetch under compute
        const _Float16* S0 = sm[cur];
        #pragma unroll
        for (int ks = 0; ks < 2; ++ks) {
            const half8 a_h  = rfrag(S0, wm + fr, ks, fg);
            const half8 a_l  = rfrag(S0, 32 + wm + fr, ks, fg);
            const half8 b_h0 = rfrag(S0, 64 + wn + fr, ks, fg);
            const half8 b_h1 = rfrag(S0, 64 + wn + 16 + fr, ks, fg);
            const half8 b_l0 = rfrag(S0, 128 + wn + fr, ks, fg);
            const half8 b_l1 = rfrag(S0, 128 + wn + 16 + fr, ks, fg);
            hh[0] = __builtin_amdgcn_mfma_f32_16x16x32_f16(a_h, b_h0, hh[0], 0, 0, 0);
            hh[1] = __builtin_amdgcn_mfma_f32_16x16x32_f16(a_h, b_h1, hh[1], 0, 0, 0);
            m1[0] = __builtin_amdgcn_mfma_f32_16x16x32_f16(a_h, b_l0, m1[0], 0, 0, 0);
            m1[1] = __builtin_amdgcn_mfma_f32_16x16x32_f16(a_h, b_l1, m1[1], 0, 0, 0);
            m2[0] = __builtin_amdgcn_mfma_f32_16x16x32_f16(a_l, b_h0, m2[0], 0, 0, 0);
            m2[1] = __builtin_amdgcn_mfma_f32_16x16x32_f16(a_l, b_h1, m2[1], 0, 0, 0);
        }
        __syncthreads();
    }

    // Epilogue. C/D layout (validated): col = lane&15, row = 4*(lane>>4)+reg.
    #pragma unroll
    for (int j = 0; j < 2; ++j) {
        const int col = n0 + wn + j * 16 + fr;
        const float bv = bias ? bias[col] : 0.0f;
        const int colr = remap1(col);
        #pragma unroll
        for (int r = 0; r < 4; ++r) {
            const int row = m0 + wm + fg * 4 + r;
            float v = hh[j][r] + (m1[j][r] + m2[j][r]) * INV_LO_SCALE + bv;
            if (RELU) v = fmaxf(v, 0.0f);
            if (WF32) Cf[(size_t)row * N + col] = v;
            if (WSPLIT) {
                const size_t o = (size_t)row * N + colr;
                const _Float16 hi = (_Float16)v;
                Ch[o] = hi;
                Cl[o] = (_Float16)((v - (float)hi) * LO_SCALE);
            }
        }
    }
}

// ---------------------------------------------------------------------------
// Fused prep: b<768: weight splitT (z=b>>8); b<1280: obs split; else CB split.
// All outputs k-interleaved.
// ---------------------------------------------------------------------------
__global__ __launch_bounds__(256) void prep_kernel(
    const float* __restrict__ W1, const float* __restrict__ W2,
    const float* __restrict__ W3, const float* __restrict__ obs,
    const float* __restrict__ CB,
    _Float16* __restrict__ T1h, _Float16* __restrict__ T1l,
    _Float16* __restrict__ T2h, _Float16* __restrict__ T2l,
    _Float16* __restrict__ T3h, _Float16* __restrict__ T3l,
    _Float16* __restrict__ Oh, _Float16* __restrict__ Ol,
    _Float16* __restrict__ CBh, _Float16* __restrict__ CBl,
    float* __restrict__ cnorm)
{
    __shared__ float tile[64][65];
    const int b = blockIdx.x, tid = threadIdx.x;

    if (b < 768) {
        const int z = b >> 8, rem = b & 255;
        const float* Wm = (z == 0) ? W1 : (z == 1) ? W2 : W3;
        _Float16* Th = (z == 0) ? T1h : (z == 1) ? T2h : T3h;
        _Float16* Tl = (z == 0) ? T1l : (z == 1) ? T2l : T3l;
        const int nb = (rem & 15) * 64, kb = (rem >> 4) * 64;
        {
            const int kr = tid >> 2, c0 = (tid & 3) * 16;
            #pragma unroll
            for (int c = 0; c < 16; c += 4) {
                float4 v = *reinterpret_cast<const float4*>(
                    &Wm[(size_t)(kb + kr) * 1024 + nb + c0 + c]);
                tile[kr][c0 + c] = v.x; tile[kr][c0 + c + 1] = v.y;
                tile[kr][c0 + c + 2] = v.z; tile[kr][c0 + c + 3] = v.w;
            }
        }
        __syncthreads();
        {
            const int nr = tid >> 2, k0 = (tid & 3) * 16;
            #pragma unroll
            for (int g = 0; g < 4; ++g) {
                const int kk = k0 + g * 4;
                half4 h, lo;
                #pragma unroll
                for (int j = 0; j < 4; ++j) {
                    const float x = tile[kk + j][nr];
                    const _Float16 hi = (_Float16)x;
                    h[j] = hi;
                    lo[j] = (_Float16)((x - (float)hi) * LO_SCALE);
                }
                const size_t o = (size_t)(nb + nr) * 1024 + kb + remap4(kk);
                *reinterpret_cast<half4*>(&Th[o]) = h;
                *reinterpret_cast<half4*>(&Tl[o]) = lo;
            }
        }
    } else if (b < 1280) {
        const size_t e0 = ((size_t)(b - 768) * 256 + tid) * 8;
        float4 a = *reinterpret_cast<const float4*>(&obs[e0]);
        float4 c = *reinterpret_cast<const float4*>(&obs[e0 + 4]);
        float xs[8] = {a.x, a.y, a.z, a.w, c.x, c.y, c.z, c.w};
        half4 h[2], lo[2];
        #pragma unroll
        for (int q = 0; q < 2; ++q)
            #pragma unroll
            for (int j = 0; j < 4; ++j) {
                const float x = xs[q * 4 + j];
                const _Float16 hi = (_Float16)x;
                h[q][j] = hi;
                lo[q][j] = (_Float16)((x - (float)hi) * LO_SCALE);
            }
        const size_t base = e0 & ~(size_t)63;
        const int r1 = remap4((int)(e0 & 63));
        const int r2 = remap4((int)((e0 + 4) & 63));
        *reinterpret_cast<half4*>(&Oh[base + r1]) = h[0];
        *reinterpret_cast<half4*>(&Oh[base + r2]) = h[1];
        *reinterpret_cast<half4*>(&Ol[base + r1]) = lo[0];
        *reinterpret_cast<half4*>(&Ol[base + r2]) = lo[1];
    } else {
        const int wv = tid >> 6, lane = tid & 63;
        const int code = (b - 1280) * 4 + wv;
        const int k0 = lane * 4;
        float4 c = *reinterpret_cast<const float4*>(&CB[(size_t)code * 256 + k0]);
        float xs[4] = {c.x, c.y, c.z, c.w};
        half4 h, lo;
        float s = 0.f;
        #pragma unroll
        for (int j = 0; j < 4; ++j) {
            const _Float16 hi = (_Float16)xs[j];
            h[j] = hi;
            lo[j] = (_Float16)((xs[j] - (float)hi) * LO_SCALE);
            s += xs[j] * xs[j];
        }
        const size_t o = (size_t)code * 256 + (k0 & ~63) + remap4(k0 & 63);
        *reinterpret_cast<half4*>(&CBh[o]) = h;
        *reinterpret_cast<half4*>(&CBl[o]) = lo;
        #pragma unroll
        for (int off = 32; off; off >>= 1) s += __shfl_down(s, off);
        if (lane == 0) cnorm[code] = s;
    }
}

// ---------------------------------------------------------------------------
// VQ: one wave per token; 8 tokens / 512-thr block; per-block loss partial.
// ---------------------------------------------------------------------------
__global__ __launch_bounds__(512) void vq_kernel(
    const _Float16* __restrict__ Fh, const _Float16* __restrict__ Fl,
    const float* __restrict__ S, const float* __restrict__ CB,
    const float* __restrict__ cnorm,
    float* __restrict__ out, float* __restrict__ pl, float* __restrict__ idx_out)
{
    const int wid = threadIdx.x >> 6, lane = threadIdx.x & 63;
    const int n = blockIdx.x * 8 + wid;

    float best = 3.4e38f;
    int bidx = 0x7fffffff;
    #pragma unroll
    for (int j = 0; j < 8; ++j) {
        const int k = j * 64 + lane;
        const float v = fmaf(-2.0f, S[(size_t)n * 512 + k], cnorm[k]);
        if (v < best) { best = v; bidx = k; }   // strict <: first occurrence
    }
    #pragma unroll
    for (int off = 32; off; off >>= 1) {
        const float ov = __shfl_down(best, off);
        const int oi = __shfl_down(bidx, off);
        if (ov < best || (ov == best && oi < bidx)) { best = ov; bidx = oi; }
    }
    bidx = __shfl(bidx, 0);
    best = __shfl(best, 0);

    // ||z||^2 (k-interleaved storage is permutation of the row -> sum invariant)
    const int base = n * 256 + lane * 4;
    half4 h4 = *reinterpret_cast<const half4*>(&Fh[base]);
    half4 l4 = *reinterpret_cast<const half4*>(&Fl[base]);
    float zn = 0.f;
    #pragma unroll
    for (int j = 0; j < 4; ++j) {
        const float z = (float)h4[j] + (float)l4[j] * INV_LO_SCALE;
        zn = fmaf(z, z, zn);
    }
    #pragma unroll
    for (int off = 32; off; off >>= 1) zn += __shfl_down(zn, off);

    float4 q4 = *reinterpret_cast<const float4*>(&CB[(size_t)bidx * 256 + lane * 4]);
    *reinterpret_cast<float4*>(&out[(size_t)n * 256 + lane * 4]) = q4;

    __shared__ float part[8];
    if (lane == 0) {
        part[wid] = zn + best;
        idx_out[n] = (float)bidx;
    }
    __syncthreads();
    if (threadIdx.x == 0) {
        float s = 0.f;
        #pragma unroll
        for (int i = 0; i < 8; ++i) s += part[i];
        pl[blockIdx.x] = s;
    }
}

__global__ __launch_bounds__(512) void finalize_kernel(
    const float* __restrict__ pl, float* __restrict__ loss_out)
{
    float s = pl[threadIdx.x];
    #pragma unroll
    for (int off = 32; off; off >>= 1) s += __shfl_down(s, off);
    __shared__ float p[8];
    if ((threadIdx.x & 63) == 0) p[threadIdx.x >> 6] = s;
    __syncthreads();
    if (threadIdx.x == 0) {
        float t = 0.f;
        #pragma unroll
        for (int i = 0; i < 8; ++i) t += p[i];
        loss_out[0] = 1.25f * t / 1048576.0f;
    }
}

// ---------------------------------------------------------------------------
extern "C" void kernel_launch(void* const* d_in, const int* in_sizes, int n_in,
                              void* d_out, int out_size, void* d_ws, size_t ws_size,
                              hipStream_t stream)
{
    const float* obs = (const float*)d_in[0];
    const float* W1  = (const float*)d_in[1];
    const float* b1  = (const float*)d_in[2];
    const float* W2  = (const float*)d_in[3];
    const float* b2  = (const float*)d_in[4];
    const float* W3  = (const float*)d_in[5];
    const float* b3  = (const float*)d_in[6];
    const float* CB  = (const float*)d_in[7];

    float* out = (float*)d_out;
    float* loss_out = out + 1048576;
    float* idx_out  = out + 1048577;

    char* Wp = (char*)d_ws;
    _Float16* Oh    = (_Float16*)(Wp + (0u  << 20));
    _Float16* Ol    = (_Float16*)(Wp + (2u  << 20));
    _Float16* W1t_h = (_Float16*)(Wp + (4u  << 20));
    _Float16* W1t_l = (_Float16*)(Wp + (6u  << 20));
    _Float16* W2t_h = (_Float16*)(Wp + (8u  << 20));
    _Float16* W2t_l = (_Float16*)(Wp + (10u << 20));
    _Float16* W3t_h = (_Float16*)(Wp + (12u << 20));
    _Float16* W3t_l = (_Float16*)(Wp + (14u << 20));
    _Float16* H1_h  = (_Float16*)(Wp + (16u << 20));
    _Float16* H1_l  = (_Float16*)(Wp + (18u << 20));
    _Float16* H2_h  = (_Float16*)(Wp + (20u << 20));
    _Float16* H2_l  = (_Float16*)(Wp + (22u << 20));
    _Float16* F_h   = (_Float16*)(Wp + (24u << 20));
    _Float16* F_l   = (_Float16*)(Wp + (26u << 20));
    float*    S     = (float*)(Wp + (28u << 20));          // 8MB
    _Float16* CB_h  = (_Float16*)(Wp + (36u << 20));
    _Float16* CB_l  = (_Float16*)(Wp + (36u << 20) + 512 * 256 * 2);
    float*    cn    = (float*)(Wp + (36u << 20) + 2 * 512 * 256 * 2);
    float*    pl    = cn + 512;

    prep_kernel<<<1408, 256, 0, stream>>>(
        W1, W2, W3, obs, CB,
        W1t_h, W1t_l, W2t_h, W2t_l, W3t_h, W3t_l,
        Oh, Ol, CB_h, CB_l, cn);

    gemm_k<true, false, true><<<dim3(16, 32), 256, 0, stream>>>(
        Oh, Ol, W1t_h, W1t_l, b1, nullptr, H1_h, H1_l, 1024, 1024);
    gemm_k<true, false, true><<<dim3(16, 32), 256, 0, stream>>>(
        H1_h, H1_l, W2t_h, W2t_l, b2, nullptr, H2_h, H2_l, 1024, 1024);
    gemm_k<false, false, true><<<dim3(16, 32), 256, 0, stream>>>(
        H2_h, H2_l, W3t_h, W3t_l, b3, nullptr, F_h, F_l, 1024, 1024);
    // S = z @ CB^T : [4096, 512], K=256 -> grid (8,128) = 1024 blocks (4/CU)
    gemm_k<false, true, false><<<dim3(8, 128), 256, 0, stream>>>(
        F_h, F_l, CB_h, CB_l, nullptr, S, nullptr, nullptr, 512, 256);

    vq_kernel<<<512, 512, 0, stream>>>(F_h, F_l, S, CB, cn, out, pl, idx_out);
    finalize_kernel<<<1, 512, 0, stream>>>(pl, loss_out);
}